// Round 5
// baseline (1591.204 us; speedup 1.0000x reference)
//
#include <hip/hip_runtime.h>
#include <hip/hip_bf16.h>

// ---------------------------------------------------------------------------
// HeteroGCN: 2-layer, 2-relation GCN. N=100k, E=1M/relation, D=64.
//
// out[d] = dinv[d]*(t[d] + sum_{(s,d)} t[s]) + b,  t = dinv .* (X@W)
//
// R3 analysis: fill2 (1-pass counting sort) was HBM-writeback bound:
// 2M random 4B scatters -> 127.8 MB WRITE_SIZE (16x amplification), 166us.
// R4: two-pass radix partition by dst. Pass A bins edges into 1024
// contiguous bucket regions (packed u32: d_low<<18 | s_tag). Pass B fills
// the final CSR; its scatter window is L2-resident (~2MB) so line writes
// coalesce before eviction. Histogram fused into count2.
// ---------------------------------------------------------------------------

#define NF   64    // feature dim
#define NB   1024  // radix buckets
#define BSH  7     // bucket = d >> BSH  (128 nodes/bucket)

// count per-(relation,dst) degrees + per-bucket histogram
__global__ void count2h(const int* __restrict__ ei1, const int* __restrict__ ei2,
                        int* __restrict__ cnt, int* __restrict__ ghist,
                        int N, int E) {
    int i = blockIdx.x * blockDim.x + threadIdx.x;
    if (i < 2 * E) {
        int d, base;
        if (i < E) { d = ei1[E + i];       base = 0; }
        else       { d = ei2[E + (i - E)]; base = N; }
        atomicAdd(&cnt[base + d], 1);
        atomicAdd(&ghist[d >> BSH], 1);
    }
}

// dinv per relation + combined per-dst count for the merged CSR scan
__global__ void dinv_sum(const int* __restrict__ cnt, float* __restrict__ dinv1,
                         float* __restrict__ dinv2, int* __restrict__ csum, int n) {
    int i = blockIdx.x * blockDim.x + threadIdx.x;
    if (i < n) {
        int c1 = cnt[i], c2 = cnt[n + i];
        dinv1[i] = rsqrtf((float)(c1 + 1));
        dinv2[i] = rsqrtf((float)(c2 + 1));
        csum[i] = c1 + c2;
    }
}

// pass 1: per-block (1024 elems) exclusive scan, block totals to bsum
__global__ void scan_blocks(const int* __restrict__ cnt, int* __restrict__ off,
                            int* __restrict__ bsum, int n) {
    __shared__ int sh[256];
    int tid = threadIdx.x;
    int base = blockIdx.x * 1024 + tid * 4;
    int c0 = (base + 0 < n) ? cnt[base + 0] : 0;
    int c1 = (base + 1 < n) ? cnt[base + 1] : 0;
    int c2 = (base + 2 < n) ? cnt[base + 2] : 0;
    int c3 = (base + 3 < n) ? cnt[base + 3] : 0;
    int tsum = c0 + c1 + c2 + c3;
    sh[tid] = tsum;
    __syncthreads();
    for (int ofs = 1; ofs < 256; ofs <<= 1) {
        int v = 0;
        if (tid >= ofs) v = sh[tid - ofs];
        __syncthreads();
        if (tid >= ofs) sh[tid] += v;
        __syncthreads();
    }
    int excl = sh[tid] - tsum;
    int run = excl;
    if (base + 0 < n) off[base + 0] = run; run += c0;
    if (base + 1 < n) off[base + 1] = run; run += c1;
    if (base + 2 < n) off[base + 2] = run; run += c2;
    if (base + 3 < n) off[base + 3] = run;
    if (tid == 255) bsum[blockIdx.x] = sh[255];
}

// pass 2: parallel exclusive scan of block sums (nb <= 256)
__global__ void scan_bsum(int* __restrict__ bsum, int nb) {
    __shared__ int sh[256];
    int tid = threadIdx.x;
    int v = (tid < nb) ? bsum[tid] : 0;
    sh[tid] = v;
    __syncthreads();
    for (int ofs = 1; ofs < 256; ofs <<= 1) {
        int u = (tid >= ofs) ? sh[tid - ofs] : 0;
        __syncthreads();
        sh[tid] += u;
        __syncthreads();
    }
    if (tid < nb) bsum[tid] = sh[tid] - v;   // exclusive
}

// pass 3: add block offsets, set off[n] = total
__global__ void scan_add(int* __restrict__ off, const int* __restrict__ bsum,
                         int n, int total) {
    int i = blockIdx.x * blockDim.x + threadIdx.x;
    if (i < n) off[i] += bsum[i >> 10];
    if (i == 0) off[n] = total;
}

__global__ void copy_int(int* __restrict__ dst, const int* __restrict__ src, int n) {
    int i = blockIdx.x * blockDim.x + threadIdx.x;
    if (i < n) dst[i] = src[i];
}

// radix pass A: bin edges into bucket regions; entry = (d & 127) << 18 | s_tag
__global__ void partA(const int* __restrict__ ei1, const int* __restrict__ ei2,
                      int* __restrict__ bcur, unsigned* __restrict__ ebuf,
                      int N, int E) {
    int i = blockIdx.x * blockDim.x + threadIdx.x;
    if (i < 2 * E) {
        int s, d;
        if (i < E) { s = ei1[i];           d = ei1[E + i]; }
        else       { s = ei2[i - E] + N;   d = ei2[E + (i - E)]; }
        int b = d >> BSH;
        int p = atomicAdd(&bcur[b], 1);
        ebuf[p] = ((unsigned)(d & ((1 << BSH) - 1)) << 18) | (unsigned)s;
    }
}

// radix pass B: fine CSR fill; bucket recovered by binary search in LDS boff
__global__ __launch_bounds__(256) void partB(
        const unsigned* __restrict__ ebuf, const int* __restrict__ boff,
        int* __restrict__ cur, int* __restrict__ msrc, int total) {
    __shared__ int sb[NB + 1];
    for (int i = threadIdx.x; i < NB; i += 256) sb[i] = boff[i];
    if (threadIdx.x == 0) sb[NB] = total;
    __syncthreads();
    int i = blockIdx.x * 256 + threadIdx.x;
    if (i < total) {
        unsigned v = ebuf[i];
        int s  = (int)(v & ((1u << 18) - 1));
        int dl = (int)(v >> 18);
        int lo = 0, hi = NB;            // invariant: sb[lo] <= i < sb[hi]
        while (hi - lo > 1) { int mid = (lo + hi) >> 1; if (sb[mid] <= i) lo = mid; else hi = mid; }
        int d = (lo << BSH) | dl;
        int p = atomicAdd(&cur[d], 1);
        msrc[p] = s;
    }
}

// Fused dual-relation GEMM: t[r] = da .* (X@Wa), t[N+r] = db .* (X@Wb)
__global__ __launch_bounds__(256) void gemm2(
        const float* __restrict__ X,
        const float* __restrict__ Wa, const float* __restrict__ Wb,
        const float* __restrict__ da, const float* __restrict__ db,
        float* __restrict__ t, int n) {
    __shared__ float wa[NF * NF];
    __shared__ float wb[NF * NF];
    for (int i = threadIdx.x; i < NF * NF; i += 256) { wa[i] = Wa[i]; wb[i] = Wb[i]; }
    __syncthreads();
    int wave = threadIdx.x >> 6;
    int lane = threadIdx.x & 63;
    for (int r = blockIdx.x * 4 + wave; r < n; r += gridDim.x * 4) {
        float xv = X[(size_t)r * NF + lane];
        float a1 = 0.f, a2 = 0.f;
        #pragma unroll
        for (int k = 0; k < NF; ++k) {
            float xk = __shfl(xv, k, 64);
            a1 = fmaf(xk, wa[k * NF + lane], a1);
            a2 = fmaf(xk, wb[k * NF + lane], a2);
        }
        t[(size_t)r * NF + lane]       = a1 * da[r];
        t[(size_t)(n + r) * NF + lane] = a2 * db[r];
    }
}

// Merged gather: one wave per node, lane per feature, masked 8-wide unroll.
// t is [2N][64]; msrc entries < N are rel-1, >= N are rel-2.
template <int RELU>
__global__ __launch_bounds__(256) void gather2(
        const float* __restrict__ t,
        const int* __restrict__ moff, const int* __restrict__ msrc,
        const float* __restrict__ da, const float* __restrict__ db,
        const float* __restrict__ bia, const float* __restrict__ bib,
        float* __restrict__ out, int n) {
    int node = blockIdx.x * 4 + (threadIdx.x >> 6);
    if (node >= n) return;
    int lane = threadIdx.x & 63;

    float self1 = t[(size_t)node * NF + lane];
    float self2 = t[(size_t)(n + node) * NF + lane];

    float acc1 = 0.f, acc2 = 0.f;
    int e0 = moff[node], e1 = moff[node + 1];
    for (int e = e0; e < e1; e += 8) {
        #pragma unroll
        for (int j = 0; j < 8; ++j) {
            int ee = e + j;
            bool v = ee < e1;
            int idx = v ? msrc[ee] : node;          // msrc padded; safe load
            float r = t[(size_t)idx * NF + lane];
            float rv = v ? r : 0.f;
            bool isB = idx >= n;
            acc1 += isB ? 0.f : rv;
            acc2 += isB ? rv : 0.f;
        }
    }
    float v = (acc1 + self1) * da[node] + (acc2 + self2) * db[node]
            + bia[lane] + bib[lane];
    if (RELU) v = fmaxf(v, 0.f);
    out[(size_t)node * NF + lane] = v;
}

extern "C" void kernel_launch(void* const* d_in, const int* in_sizes, int n_in,
                              void* d_out, int out_size, void* d_ws, size_t ws_size,
                              hipStream_t stream) {
    const float* x   = (const float*)d_in[0];
    const int*   ei1 = (const int*)d_in[1];
    const int*   ei2 = (const int*)d_in[2];
    const float* W1a = (const float*)d_in[3];
    const float* b1a = (const float*)d_in[4];
    const float* W1b = (const float*)d_in[5];
    const float* b1b = (const float*)d_in[6];
    const float* W2a = (const float*)d_in[7];
    const float* b2a = (const float*)d_in[8];
    const float* W2b = (const float*)d_in[9];
    const float* b2b = (const float*)d_in[10];

    const int N = in_sizes[0] / NF;
    const int E = in_sizes[1] / 2;
    float* out = (float*)d_out;

    // workspace carve-out
    char* w = (char*)d_ws;
    auto alloc = [&](size_t bytes) {
        char* p = w;
        w += (bytes + 255) & ~(size_t)255;
        return p;
    };
    float*    t     = (float*)alloc((size_t)2 * N * NF * sizeof(float)); // [2N][64]
    float*    dinv1 = (float*)alloc((size_t)N * sizeof(float));
    float*    dinv2 = (float*)alloc((size_t)N * sizeof(float));
    int*      cnt   = (int*)alloc((size_t)2 * N * sizeof(int));   // rel1|rel2 degrees
    int*      ghist = (int*)alloc((size_t)NB * sizeof(int));      // bucket histogram
    int*      csum  = (int*)alloc((size_t)N * sizeof(int));
    int*      moff  = (int*)alloc((size_t)(N + 1) * sizeof(int));
    int*      boff  = (int*)alloc((size_t)(NB + 1) * sizeof(int));
    int*      cur   = (int*)alloc((size_t)N * sizeof(int));
    int*      bcur  = (int*)alloc((size_t)NB * sizeof(int));
    int*      msrc  = (int*)alloc(((size_t)2 * E + 8) * sizeof(int));   // +8 pad
    unsigned* ebuf  = (unsigned*)alloc((size_t)2 * E * sizeof(unsigned));
    const int nb = (N + 1023) / 1024;
    int*      bsum  = (int*)alloc((size_t)nb * sizeof(int));
    int*      bscr  = (int*)alloc(256 * sizeof(int));             // scratch bsum

    const int g2E = (2 * E + 255) / 256;
    const int gN  = (N + 255) / 256;

    // ---- degrees + bucket histogram ----
    hipMemsetAsync(cnt, 0, (size_t)2 * N * sizeof(int), stream);
    hipMemsetAsync(ghist, 0, (size_t)NB * sizeof(int), stream);
    count2h<<<g2E, 256, 0, stream>>>(ei1, ei2, cnt, ghist, N, E);
    dinv_sum<<<gN, 256, 0, stream>>>(cnt, dinv1, dinv2, csum, N);

    // ---- merged CSR offsets (scan over per-dst combined counts) ----
    scan_blocks<<<nb, 256, 0, stream>>>(csum, moff, bsum, N);
    scan_bsum<<<1, 256, 0, stream>>>(bsum, nb);
    scan_add<<<gN, 256, 0, stream>>>(moff, bsum, N, 2 * E);
    copy_int<<<gN, 256, 0, stream>>>(cur, moff, N);

    // ---- bucket offsets (single-block scan of 1024 counts) ----
    scan_blocks<<<1, 256, 0, stream>>>(ghist, boff, bscr, NB);
    copy_int<<<(NB + 255) / 256, 256, 0, stream>>>(bcur, boff, NB);

    // ---- two-pass radix CSR fill ----
    partA<<<g2E, 256, 0, stream>>>(ei1, ei2, bcur, ebuf, N, E);
    partB<<<g2E, 256, 0, stream>>>(ebuf, boff, cur, msrc, 2 * E);

    const int gNode = (N + 3) / 4;

    // ---- layer 1: h = relu(conv_r1(x) + conv_r2(x)); h lives in d_out ----
    gemm2<<<1024, 256, 0, stream>>>(x, W1a, W1b, dinv1, dinv2, t, N);
    gather2<1><<<gNode, 256, 0, stream>>>(t, moff, msrc, dinv1, dinv2,
                                          b1a, b1b, out, N);

    // ---- layer 2: out = conv_r1(h) + conv_r2(h) ----
    gemm2<<<1024, 256, 0, stream>>>(out, W2a, W2b, dinv1, dinv2, t, N);
    gather2<0><<<gNode, 256, 0, stream>>>(t, moff, msrc, dinv1, dinv2,
                                          b2a, b2b, out, N);
}

// Round 7
// 571.091 us; speedup vs baseline: 2.7863x; 2.7863x over previous
//
#include <hip/hip_runtime.h>
#include <hip/hip_bf16.h>

// ---------------------------------------------------------------------------
// HeteroGCN: 2-layer, 2-relation GCN. N=100k, E=1M/relation, D=64.
//
// out[d] = dinv[d]*(t[d] + sum_{(s,d)} t[s]) + b,  t = dinv .* (X@W)
//
// R5 lesson (measured): 2M global atomics on ~1K addresses = 538us kernel,
// 111MB memory-side RMW writeback. Even 100K-address atomics cost ~150us.
// R6: CSR build with ZERO global atomics:
//   hista: per-WG LDS histogram of 196 coarse buckets (512 nodes each)
//          -> histT[bucket][wg] (plain stores)
//   scan : exclusive scan of histT (50K ints) -> disjoint per-(b,wg) regions
//   scata: re-read edges, LDS-bump-allocate into ebuf (packed dlow|srctag)
//   fineb: one WG per bucket: LDS per-(rel,node) hist -> dinv + moff written
//          directly (no N-scan!), LDS-staged scatter -> coalesced msrc write.
// Degree counting, dinv, moff all fused into fineb. gather/gemm unchanged.
// ---------------------------------------------------------------------------

#define NF     64      // feature dim
#define CB_SH  9       // coarse bucket = d >> 9  (512 nodes/bucket)
#define CBN    512     // nodes per coarse bucket
#define NWG_A  256     // workgroups in hista/scata
#define CAP    13312   // LDS staging capacity (entries); mean 10240, +30 sigma

// ---- pass A1: per-WG coarse histogram (LDS atomics only) ----
__global__ __launch_bounds__(256) void hista(
        const int* __restrict__ ei1, const int* __restrict__ ei2,
        int* __restrict__ histT, int N, int E, int nc, int chunk) {
    __shared__ int h[256];
    int tid = threadIdx.x;
    for (int i = tid; i < 256; i += 256) h[i] = 0;
    __syncthreads();
    int E2 = 2 * E;
    int beg = blockIdx.x * chunk;
    int end = min(beg + chunk, E2);
    for (int i = beg + tid; i < end; i += 256) {
        int d = (i < E) ? ei1[E + i] : ei2[E + (i - E)];
        atomicAdd(&h[d >> CB_SH], 1);                 // LDS atomic
    }
    __syncthreads();
    for (int b = tid; b < nc; b += 256)
        histT[b * NWG_A + blockIdx.x] = h[b];         // plain store
}

// ---- scan helpers (1024 elems/block) ----
__global__ void scan_blocks(const int* __restrict__ cnt, int* __restrict__ off,
                            int* __restrict__ bsum, int n) {
    __shared__ int sh[256];
    int tid = threadIdx.x;
    int base = blockIdx.x * 1024 + tid * 4;
    int c0 = (base + 0 < n) ? cnt[base + 0] : 0;
    int c1 = (base + 1 < n) ? cnt[base + 1] : 0;
    int c2 = (base + 2 < n) ? cnt[base + 2] : 0;
    int c3 = (base + 3 < n) ? cnt[base + 3] : 0;
    int tsum = c0 + c1 + c2 + c3;
    sh[tid] = tsum;
    __syncthreads();
    for (int ofs = 1; ofs < 256; ofs <<= 1) {
        int v = 0;
        if (tid >= ofs) v = sh[tid - ofs];
        __syncthreads();
        if (tid >= ofs) sh[tid] += v;
        __syncthreads();
    }
    int excl = sh[tid] - tsum;
    int run = excl;
    if (base + 0 < n) off[base + 0] = run; run += c0;
    if (base + 1 < n) off[base + 1] = run; run += c1;
    if (base + 2 < n) off[base + 2] = run; run += c2;
    if (base + 3 < n) off[base + 3] = run;
    if (tid == 255) bsum[blockIdx.x] = sh[255];
}

__global__ void scan_bsum(int* __restrict__ bsum, int nb) {
    __shared__ int sh[256];
    int tid = threadIdx.x;
    int v = (tid < nb) ? bsum[tid] : 0;
    sh[tid] = v;
    __syncthreads();
    for (int ofs = 1; ofs < 256; ofs <<= 1) {
        int u = (tid >= ofs) ? sh[tid - ofs] : 0;
        __syncthreads();
        sh[tid] += u;
        __syncthreads();
    }
    if (tid < nb) bsum[tid] = sh[tid] - v;   // exclusive
}

__global__ void scan_add(int* __restrict__ off, const int* __restrict__ bsum,
                         int n, int total) {
    int i = blockIdx.x * blockDim.x + threadIdx.x;
    if (i < n) off[i] += bsum[i >> 10];
    if (i == 0) off[n] = total;
}

// ---- pass A2: scatter into bucket regions (LDS bump-alloc, no glb atomics) ----
__global__ __launch_bounds__(256) void scata(
        const int* __restrict__ ei1, const int* __restrict__ ei2,
        const int* __restrict__ gbase, unsigned* __restrict__ ebuf,
        int N, int E, int nc, int chunk) {
    __shared__ int cur[256];
    int tid = threadIdx.x;
    for (int b = tid; b < nc; b += 256)
        cur[b] = gbase[b * NWG_A + blockIdx.x];       // my disjoint region starts
    __syncthreads();
    int E2 = 2 * E;
    int beg = blockIdx.x * chunk;
    int end = min(beg + chunk, E2);
    for (int i = beg + tid; i < end; i += 256) {
        int s, d;
        if (i < E) { s = ei1[i];         d = ei1[E + i]; }
        else       { s = ei2[i - E] + N; d = ei2[E + (i - E)]; }
        int b = d >> CB_SH;
        int p = atomicAdd(&cur[b], 1);                // LDS atomic
        ebuf[p] = ((unsigned)(d & (CBN - 1)) << 18) | (unsigned)s;
    }
}

// ---- pass B: per-bucket fine sort + degrees + dinv + moff, staged in LDS ----
__global__ __launch_bounds__(256) void fineb(
        const unsigned* __restrict__ ebuf, const int* __restrict__ gbase,
        int* __restrict__ msrc, int* __restrict__ moff,
        float* __restrict__ dinv1, float* __restrict__ dinv2,
        int N, int E2, int nc) {
    __shared__ unsigned stage[CAP];
    __shared__ int h2[2 * CBN];     // [rel][dlow] counts
    __shared__ int lofs[CBN + 1];   // per-node combined exclusive offsets
    __shared__ int curl[CBN];
    __shared__ int sc[256];

    int b = blockIdx.x, tid = threadIdx.x;
    int w0 = gbase[b * NWG_A];
    int w1 = (b + 1 < nc) ? gbase[(b + 1) * NWG_A] : E2;
    int wsz = w1 - w0;
    int nodebase = b << CB_SH;
    int nloc = min(CBN, N - nodebase);

    for (int i = tid; i < 2 * CBN; i += 256) h2[i] = 0;
    __syncthreads();

    // 1. per-(rel,node) histogram (coalesced global reads, LDS atomics)
    for (int i = tid; i < wsz; i += 256) {
        unsigned v = ebuf[w0 + i];
        int s = (int)(v & ((1u << 18) - 1));
        int dl = (int)(v >> 18);
        atomicAdd(&h2[(s >= N ? CBN : 0) + dl], 1);
    }
    __syncthreads();

    // 2. scan combined per-node counts (512 via 2/thread)
    int dl0 = tid * 2, dl1 = tid * 2 + 1;
    int c0 = h2[dl0] + h2[CBN + dl0];
    int c1 = h2[dl1] + h2[CBN + dl1];
    sc[tid] = c0 + c1;
    __syncthreads();
    for (int ofs = 1; ofs < 256; ofs <<= 1) {
        int v = (tid >= ofs) ? sc[tid - ofs] : 0;
        __syncthreads();
        sc[tid] += v;
        __syncthreads();
    }
    int excl = sc[tid] - (c0 + c1);
    lofs[dl0] = excl;
    lofs[dl1] = excl + c0;
    if (tid == 255) lofs[CBN] = sc[255];
    __syncthreads();

    // 3. dinv + moff for this bucket's nodes (coalesced stores, no N-scan)
    for (int dl = tid; dl < nloc; dl += 256) {
        int d = nodebase + dl;
        dinv1[d] = rsqrtf((float)(h2[dl] + 1));
        dinv2[d] = rsqrtf((float)(h2[CBN + dl] + 1));
        moff[d] = w0 + lofs[dl];
    }
    if (b == nc - 1 && tid == 0) moff[N] = E2;

    for (int i = tid; i < CBN; i += 256) curl[i] = lofs[i];
    __syncthreads();

    // 4. fine scatter: LDS-staged (coalesced final write); fallback if huge
    if (wsz <= CAP) {
        for (int i = tid; i < wsz; i += 256) {
            unsigned v = ebuf[w0 + i];            // L2-hot second read
            int s = (int)(v & ((1u << 18) - 1));
            int dl = (int)(v >> 18);
            int p = atomicAdd(&curl[dl], 1);      // LDS atomic
            stage[p] = (unsigned)s;
        }
        __syncthreads();
        for (int i = tid; i < wsz; i += 256) msrc[w0 + i] = (int)stage[i];
    } else {                                      // safety net (never expected)
        for (int i = tid; i < wsz; i += 256) {
            unsigned v = ebuf[w0 + i];
            int s = (int)(v & ((1u << 18) - 1));
            int dl = (int)(v >> 18);
            int p = atomicAdd(&curl[dl], 1);
            msrc[w0 + p] = s;
        }
    }
}

// ---- dense: t[r] = da .* (X@Wa), t[N+r] = db .* (X@Wb) ----
__global__ __launch_bounds__(256) void gemm2(
        const float* __restrict__ X,
        const float* __restrict__ Wa, const float* __restrict__ Wb,
        const float* __restrict__ da, const float* __restrict__ db,
        float* __restrict__ t, int n) {
    __shared__ float wa[NF * NF];
    __shared__ float wb[NF * NF];
    for (int i = threadIdx.x; i < NF * NF; i += 256) { wa[i] = Wa[i]; wb[i] = Wb[i]; }
    __syncthreads();
    int wave = threadIdx.x >> 6;
    int lane = threadIdx.x & 63;
    for (int r = blockIdx.x * 4 + wave; r < n; r += gridDim.x * 4) {
        float xv = X[(size_t)r * NF + lane];
        float a1 = 0.f, a2 = 0.f;
        #pragma unroll
        for (int k = 0; k < NF; ++k) {
            float xk = __shfl(xv, k, 64);
            a1 = fmaf(xk, wa[k * NF + lane], a1);
            a2 = fmaf(xk, wb[k * NF + lane], a2);
        }
        t[(size_t)r * NF + lane]       = a1 * da[r];
        t[(size_t)(n + r) * NF + lane] = a2 * db[r];
    }
}

// ---- merged gather: wave/node, lane/feature, masked 8-wide unroll ----
template <int RELU>
__global__ __launch_bounds__(256) void gather2(
        const float* __restrict__ t,
        const int* __restrict__ moff, const int* __restrict__ msrc,
        const float* __restrict__ da, const float* __restrict__ db,
        const float* __restrict__ bia, const float* __restrict__ bib,
        float* __restrict__ out, int n) {
    int node = blockIdx.x * 4 + (threadIdx.x >> 6);
    if (node >= n) return;
    int lane = threadIdx.x & 63;

    float self1 = t[(size_t)node * NF + lane];
    float self2 = t[(size_t)(n + node) * NF + lane];

    float acc1 = 0.f, acc2 = 0.f;
    int e0 = moff[node], e1 = moff[node + 1];
    for (int e = e0; e < e1; e += 8) {
        #pragma unroll
        for (int j = 0; j < 8; ++j) {
            int ee = e + j;
            bool v = ee < e1;
            int idx = v ? msrc[ee] : node;          // msrc padded; safe load
            float r = t[(size_t)idx * NF + lane];
            float rv = v ? r : 0.f;
            bool isB = idx >= n;
            acc1 += isB ? 0.f : rv;
            acc2 += isB ? rv : 0.f;
        }
    }
    float v = (acc1 + self1) * da[node] + (acc2 + self2) * db[node]
            + bia[lane] + bib[lane];
    if (RELU) v = fmaxf(v, 0.f);
    out[(size_t)node * NF + lane] = v;
}

extern "C" void kernel_launch(void* const* d_in, const int* in_sizes, int n_in,
                              void* d_out, int out_size, void* d_ws, size_t ws_size,
                              hipStream_t stream) {
    const float* x   = (const float*)d_in[0];
    const int*   ei1 = (const int*)d_in[1];
    const int*   ei2 = (const int*)d_in[2];
    const float* W1a = (const float*)d_in[3];
    const float* b1a = (const float*)d_in[4];
    const float* W1b = (const float*)d_in[5];
    const float* b1b = (const float*)d_in[6];
    const float* W2a = (const float*)d_in[7];
    const float* b2a = (const float*)d_in[8];
    const float* W2b = (const float*)d_in[9];
    const float* b2b = (const float*)d_in[10];

    const int N  = in_sizes[0] / NF;
    const int E  = in_sizes[1] / 2;
    const int E2 = 2 * E;
    float* out = (float*)d_out;

    const int nc    = (N + CBN - 1) / CBN;          // 196 coarse buckets
    const int chunk = (E2 + NWG_A - 1) / NWG_A;     // edges per pass-A WG
    const int nTot  = nc * NWG_A;                   // histT elements

    // workspace carve-out
    char* w = (char*)d_ws;
    auto alloc = [&](size_t bytes) {
        char* p = w;
        w += (bytes + 255) & ~(size_t)255;
        return p;
    };
    float*    t     = (float*)alloc((size_t)2 * N * NF * sizeof(float)); // [2N][64]
    float*    dinv1 = (float*)alloc((size_t)N * sizeof(float));
    float*    dinv2 = (float*)alloc((size_t)N * sizeof(float));
    int*      moff  = (int*)alloc((size_t)(N + 1) * sizeof(int));
    int*      msrc  = (int*)alloc(((size_t)E2 + 8) * sizeof(int));      // +8 pad
    unsigned* ebuf  = (unsigned*)alloc((size_t)E2 * sizeof(unsigned));
    int*      histT = (int*)alloc((size_t)(nTot + 1) * sizeof(int));
    int*      bsum  = (int*)alloc(256 * sizeof(int));

    // ---- atomic-free CSR build ----
    hista<<<NWG_A, 256, 0, stream>>>(ei1, ei2, histT, N, E, nc, chunk);
    const int nbs = (nTot + 1023) / 1024;           // 49 blocks
    scan_blocks<<<nbs, 256, 0, stream>>>(histT, histT, bsum, nTot);
    scan_bsum<<<1, 256, 0, stream>>>(bsum, nbs);
    scan_add<<<(nTot + 255) / 256, 256, 0, stream>>>(histT, bsum, nTot, E2);
    scata<<<NWG_A, 256, 0, stream>>>(ei1, ei2, histT, ebuf, N, E, nc, chunk);
    fineb<<<nc, 256, 0, stream>>>(ebuf, histT, msrc, moff, dinv1, dinv2, N, E2, nc);

    const int gNode = (N + 3) / 4;

    // ---- layer 1: h = relu(conv_r1(x) + conv_r2(x)); h lives in d_out ----
    gemm2<<<1024, 256, 0, stream>>>(x, W1a, W1b, dinv1, dinv2, t, N);
    gather2<1><<<gNode, 256, 0, stream>>>(t, moff, msrc, dinv1, dinv2,
                                          b1a, b1b, out, N);

    // ---- layer 2: out = conv_r1(h) + conv_r2(h) ----
    gemm2<<<1024, 256, 0, stream>>>(out, W2a, W2b, dinv1, dinv2, t, N);
    gather2<0><<<gNode, 256, 0, stream>>>(t, moff, msrc, dinv1, dinv2,
                                          b2a, b2b, out, N);
}

// Round 13
// 560.468 us; speedup vs baseline: 2.8391x; 1.0190x over previous
//
#include <hip/hip_runtime.h>
#include <hip/hip_bf16.h>

// ---------------------------------------------------------------------------
// HeteroGCN: 2-layer, 2-relation GCN. N=100k, E=1M/relation, D=64.
//
// out[d] = dinv[d]*(t[d] + sum_{(s,d)} t[s]) + b,  t = dinv .* (X@W)
//
// R7 measured: atomic-free CSR build works (571us total). gather2 = 2x135us,
// 270MB L2-miss fetch (2 x 128B lines per fp32 row), 2.24 TB/s, VALU 42%,
// occupancy 75% -> line-request-rate/MLP bound, not BW or VALU saturated.
// R8: bf16 t-table. Row = 128B = ONE line request per edge, half the L2-miss
// bytes. fp32 accumulation everywhere; only t storage is quantized.
// CSR build and all other kernels unchanged (attribution).
// ---------------------------------------------------------------------------

#define NF     64      // feature dim
#define CB_SH  9       // coarse bucket = d >> 9  (512 nodes/bucket)
#define CBN    512     // nodes per coarse bucket
#define NWG_A  256     // workgroups in hista/scata
#define CAP    13312   // LDS staging capacity (entries); mean 10240, +30 sigma

// ---- pass A1: per-WG coarse histogram (LDS atomics only) ----
__global__ __launch_bounds__(256) void hista(
        const int* __restrict__ ei1, const int* __restrict__ ei2,
        int* __restrict__ histT, int N, int E, int nc, int chunk) {
    __shared__ int h[256];
    int tid = threadIdx.x;
    for (int i = tid; i < 256; i += 256) h[i] = 0;
    __syncthreads();
    int E2 = 2 * E;
    int beg = blockIdx.x * chunk;
    int end = min(beg + chunk, E2);
    for (int i = beg + tid; i < end; i += 256) {
        int d = (i < E) ? ei1[E + i] : ei2[E + (i - E)];
        atomicAdd(&h[d >> CB_SH], 1);                 // LDS atomic
    }
    __syncthreads();
    for (int b = tid; b < nc; b += 256)
        histT[b * NWG_A + blockIdx.x] = h[b];         // plain store
}

// ---- scan helpers (1024 elems/block) ----
__global__ void scan_blocks(const int* __restrict__ cnt, int* __restrict__ off,
                            int* __restrict__ bsum, int n) {
    __shared__ int sh[256];
    int tid = threadIdx.x;
    int base = blockIdx.x * 1024 + tid * 4;
    int c0 = (base + 0 < n) ? cnt[base + 0] : 0;
    int c1 = (base + 1 < n) ? cnt[base + 1] : 0;
    int c2 = (base + 2 < n) ? cnt[base + 2] : 0;
    int c3 = (base + 3 < n) ? cnt[base + 3] : 0;
    int tsum = c0 + c1 + c2 + c3;
    sh[tid] = tsum;
    __syncthreads();
    for (int ofs = 1; ofs < 256; ofs <<= 1) {
        int v = 0;
        if (tid >= ofs) v = sh[tid - ofs];
        __syncthreads();
        if (tid >= ofs) sh[tid] += v;
        __syncthreads();
    }
    int excl = sh[tid] - tsum;
    int run = excl;
    if (base + 0 < n) off[base + 0] = run; run += c0;
    if (base + 1 < n) off[base + 1] = run; run += c1;
    if (base + 2 < n) off[base + 2] = run; run += c2;
    if (base + 3 < n) off[base + 3] = run;
    if (tid == 255) bsum[blockIdx.x] = sh[255];
}

__global__ void scan_bsum(int* __restrict__ bsum, int nb) {
    __shared__ int sh[256];
    int tid = threadIdx.x;
    int v = (tid < nb) ? bsum[tid] : 0;
    sh[tid] = v;
    __syncthreads();
    for (int ofs = 1; ofs < 256; ofs <<= 1) {
        int u = (tid >= ofs) ? sh[tid - ofs] : 0;
        __syncthreads();
        sh[tid] += u;
        __syncthreads();
    }
    if (tid < nb) bsum[tid] = sh[tid] - v;   // exclusive
}

__global__ void scan_add(int* __restrict__ off, const int* __restrict__ bsum,
                         int n, int total) {
    int i = blockIdx.x * blockDim.x + threadIdx.x;
    if (i < n) off[i] += bsum[i >> 10];
    if (i == 0) off[n] = total;
}

// ---- pass A2: scatter into bucket regions (LDS bump-alloc, no glb atomics) ----
__global__ __launch_bounds__(256) void scata(
        const int* __restrict__ ei1, const int* __restrict__ ei2,
        const int* __restrict__ gbase, unsigned* __restrict__ ebuf,
        int N, int E, int nc, int chunk) {
    __shared__ int cur[256];
    int tid = threadIdx.x;
    for (int b = tid; b < nc; b += 256)
        cur[b] = gbase[b * NWG_A + blockIdx.x];       // my disjoint region starts
    __syncthreads();
    int E2 = 2 * E;
    int beg = blockIdx.x * chunk;
    int end = min(beg + chunk, E2);
    for (int i = beg + tid; i < end; i += 256) {
        int s, d;
        if (i < E) { s = ei1[i];         d = ei1[E + i]; }
        else       { s = ei2[i - E] + N; d = ei2[E + (i - E)]; }
        int b = d >> CB_SH;
        int p = atomicAdd(&cur[b], 1);                // LDS atomic
        ebuf[p] = ((unsigned)(d & (CBN - 1)) << 18) | (unsigned)s;
    }
}

// ---- pass B: per-bucket fine sort + degrees + dinv + moff, staged in LDS ----
__global__ __launch_bounds__(256) void fineb(
        const unsigned* __restrict__ ebuf, const int* __restrict__ gbase,
        int* __restrict__ msrc, int* __restrict__ moff,
        float* __restrict__ dinv1, float* __restrict__ dinv2,
        int N, int E2, int nc) {
    __shared__ unsigned stage[CAP];
    __shared__ int h2[2 * CBN];     // [rel][dlow] counts
    __shared__ int lofs[CBN + 1];   // per-node combined exclusive offsets
    __shared__ int curl[CBN];
    __shared__ int sc[256];

    int b = blockIdx.x, tid = threadIdx.x;
    int w0 = gbase[b * NWG_A];
    int w1 = (b + 1 < nc) ? gbase[(b + 1) * NWG_A] : E2;
    int wsz = w1 - w0;
    int nodebase = b << CB_SH;
    int nloc = min(CBN, N - nodebase);

    for (int i = tid; i < 2 * CBN; i += 256) h2[i] = 0;
    __syncthreads();

    // 1. per-(rel,node) histogram (coalesced global reads, LDS atomics)
    for (int i = tid; i < wsz; i += 256) {
        unsigned v = ebuf[w0 + i];
        int s = (int)(v & ((1u << 18) - 1));
        int dl = (int)(v >> 18);
        atomicAdd(&h2[(s >= N ? CBN : 0) + dl], 1);
    }
    __syncthreads();

    // 2. scan combined per-node counts (512 via 2/thread)
    int dl0 = tid * 2, dl1 = tid * 2 + 1;
    int c0 = h2[dl0] + h2[CBN + dl0];
    int c1 = h2[dl1] + h2[CBN + dl1];
    sc[tid] = c0 + c1;
    __syncthreads();
    for (int ofs = 1; ofs < 256; ofs <<= 1) {
        int v = (tid >= ofs) ? sc[tid - ofs] : 0;
        __syncthreads();
        sc[tid] += v;
        __syncthreads();
    }
    int excl = sc[tid] - (c0 + c1);
    lofs[dl0] = excl;
    lofs[dl1] = excl + c0;
    if (tid == 255) lofs[CBN] = sc[255];
    __syncthreads();

    // 3. dinv + moff for this bucket's nodes (coalesced stores, no N-scan)
    for (int dl = tid; dl < nloc; dl += 256) {
        int d = nodebase + dl;
        dinv1[d] = rsqrtf((float)(h2[dl] + 1));
        dinv2[d] = rsqrtf((float)(h2[CBN + dl] + 1));
        moff[d] = w0 + lofs[dl];
    }
    if (b == nc - 1 && tid == 0) moff[N] = E2;

    for (int i = tid; i < CBN; i += 256) curl[i] = lofs[i];
    __syncthreads();

    // 4. fine scatter: LDS-staged (coalesced final write); fallback if huge
    if (wsz <= CAP) {
        for (int i = tid; i < wsz; i += 256) {
            unsigned v = ebuf[w0 + i];            // L2-hot second read
            int s = (int)(v & ((1u << 18) - 1));
            int dl = (int)(v >> 18);
            int p = atomicAdd(&curl[dl], 1);      // LDS atomic
            stage[p] = (unsigned)s;
        }
        __syncthreads();
        for (int i = tid; i < wsz; i += 256) msrc[w0 + i] = (int)stage[i];
    } else {                                      // safety net (never expected)
        for (int i = tid; i < wsz; i += 256) {
            unsigned v = ebuf[w0 + i];
            int s = (int)(v & ((1u << 18) - 1));
            int dl = (int)(v >> 18);
            int p = atomicAdd(&curl[dl], 1);
            msrc[w0 + p] = s;
        }
    }
}

// ---- dense: t[r] = bf16(da .* (X@Wa)), t[N+r] = bf16(db .* (X@Wb)) ----
__global__ __launch_bounds__(256) void gemm2(
        const float* __restrict__ X,
        const float* __restrict__ Wa, const float* __restrict__ Wb,
        const float* __restrict__ da, const float* __restrict__ db,
        __hip_bfloat16* __restrict__ t, int n) {
    __shared__ float wa[NF * NF];
    __shared__ float wb[NF * NF];
    for (int i = threadIdx.x; i < NF * NF; i += 256) { wa[i] = Wa[i]; wb[i] = Wb[i]; }
    __syncthreads();
    int wave = threadIdx.x >> 6;
    int lane = threadIdx.x & 63;
    for (int r = blockIdx.x * 4 + wave; r < n; r += gridDim.x * 4) {
        float xv = X[(size_t)r * NF + lane];
        float a1 = 0.f, a2 = 0.f;
        #pragma unroll
        for (int k = 0; k < NF; ++k) {
            float xk = __shfl(xv, k, 64);
            a1 = fmaf(xk, wa[k * NF + lane], a1);
            a2 = fmaf(xk, wb[k * NF + lane], a2);
        }
        t[(size_t)r * NF + lane]       = __float2bfloat16(a1 * da[r]);
        t[(size_t)(n + r) * NF + lane] = __float2bfloat16(a2 * db[r]);
    }
}

// ---- merged gather: wave/node, lane/feature, masked 8-wide unroll ----
// t rows are bf16 (128B = one cache line per edge); accumulation fp32.
template <int RELU>
__global__ __launch_bounds__(256) void gather2(
        const __hip_bfloat16* __restrict__ t,
        const int* __restrict__ moff, const int* __restrict__ msrc,
        const float* __restrict__ da, const float* __restrict__ db,
        const float* __restrict__ bia, const float* __restrict__ bib,
        float* __restrict__ out, int n) {
    int node = blockIdx.x * 4 + (threadIdx.x >> 6);
    if (node >= n) return;
    int lane = threadIdx.x & 63;

    float self1 = __bfloat162float(t[(size_t)node * NF + lane]);
    float self2 = __bfloat162float(t[(size_t)(n + node) * NF + lane]);

    float acc1 = 0.f, acc2 = 0.f;
    int e0 = moff[node], e1 = moff[node + 1];
    for (int e = e0; e < e1; e += 8) {
        #pragma unroll
        for (int j = 0; j < 8; ++j) {
            int ee = e + j;
            bool v = ee < e1;
            int idx = v ? msrc[ee] : node;          // msrc padded; safe load
            float r = __bfloat162float(t[(size_t)idx * NF + lane]);
            float rv = v ? r : 0.f;
            bool isB = idx >= n;
            acc1 += isB ? 0.f : rv;
            acc2 += isB ? rv : 0.f;
        }
    }
    float v = (acc1 + self1) * da[node] + (acc2 + self2) * db[node]
            + bia[lane] + bib[lane];
    if (RELU) v = fmaxf(v, 0.f);
    out[(size_t)node * NF + lane] = v;
}

extern "C" void kernel_launch(void* const* d_in, const int* in_sizes, int n_in,
                              void* d_out, int out_size, void* d_ws, size_t ws_size,
                              hipStream_t stream) {
    const float* x   = (const float*)d_in[0];
    const int*   ei1 = (const int*)d_in[1];
    const int*   ei2 = (const int*)d_in[2];
    const float* W1a = (const float*)d_in[3];
    const float* b1a = (const float*)d_in[4];
    const float* W1b = (const float*)d_in[5];
    const float* b1b = (const float*)d_in[6];
    const float* W2a = (const float*)d_in[7];
    const float* b2a = (const float*)d_in[8];
    const float* W2b = (const float*)d_in[9];
    const float* b2b = (const float*)d_in[10];

    const int N  = in_sizes[0] / NF;
    const int E  = in_sizes[1] / 2;
    const int E2 = 2 * E;
    float* out = (float*)d_out;

    const int nc    = (N + CBN - 1) / CBN;          // 196 coarse buckets
    const int chunk = (E2 + NWG_A - 1) / NWG_A;     // edges per pass-A WG
    const int nTot  = nc * NWG_A;                   // histT elements

    // workspace carve-out
    char* w = (char*)d_ws;
    auto alloc = [&](size_t bytes) {
        char* p = w;
        w += (bytes + 255) & ~(size_t)255;
        return p;
    };
    __hip_bfloat16* t = (__hip_bfloat16*)alloc((size_t)2 * N * NF * sizeof(__hip_bfloat16));
    float*    dinv1 = (float*)alloc((size_t)N * sizeof(float));
    float*    dinv2 = (float*)alloc((size_t)N * sizeof(float));
    int*      moff  = (int*)alloc((size_t)(N + 1) * sizeof(int));
    int*      msrc  = (int*)alloc(((size_t)E2 + 8) * sizeof(int));      // +8 pad
    unsigned* ebuf  = (unsigned*)alloc((size_t)E2 * sizeof(unsigned));
    int*      histT = (int*)alloc((size_t)(nTot + 1) * sizeof(int));
    int*      bsum  = (int*)alloc(256 * sizeof(int));

    // ---- atomic-free CSR build ----
    hista<<<NWG_A, 256, 0, stream>>>(ei1, ei2, histT, N, E, nc, chunk);
    const int nbs = (nTot + 1023) / 1024;           // 49 blocks
    scan_blocks<<<nbs, 256, 0, stream>>>(histT, histT, bsum, nTot);
    scan_bsum<<<1, 256, 0, stream>>>(bsum, nbs);
    scan_add<<<(nTot + 255) / 256, 256, 0, stream>>>(histT, bsum, nTot, E2);
    scata<<<NWG_A, 256, 0, stream>>>(ei1, ei2, histT, ebuf, N, E, nc, chunk);
    fineb<<<nc, 256, 0, stream>>>(ebuf, histT, msrc, moff, dinv1, dinv2, N, E2, nc);

    const int gNode = (N + 3) / 4;

    // ---- layer 1: h = relu(conv_r1(x) + conv_r2(x)); h lives in d_out ----
    gemm2<<<1024, 256, 0, stream>>>(x, W1a, W1b, dinv1, dinv2, t, N);
    gather2<1><<<gNode, 256, 0, stream>>>(t, moff, msrc, dinv1, dinv2,
                                          b1a, b1b, out, N);

    // ---- layer 2: out = conv_r1(h) + conv_r2(h) ----
    gemm2<<<1024, 256, 0, stream>>>(out, W2a, W2b, dinv1, dinv2, t, N);
    gather2<0><<<gNode, 256, 0, stream>>>(t, moff, msrc, dinv1, dinv2,
                                          b2a, b2b, out, N);
}